// Round 1
// baseline (194.697 us; speedup 1.0000x reference)
//
#include <hip/hip_runtime.h>
#include <hip/hip_bf16.h>
#include <stdint.h>

#define DM 1024
#define NS 16
#define LSEQ 4096
#define NB 4
#define MTOT (NB*LSEQ)   // 16384
#define NC 128           // scan chunks per sequence
#define LC 32            // LSEQ/NC

typedef __attribute__((ext_vector_type(8))) short bf16x8;
typedef __attribute__((ext_vector_type(4))) float f32x4;

__device__ __forceinline__ unsigned short f2bf(float f) {
    unsigned int u = __float_as_uint(f);
    unsigned int r = (u + 0x7FFFu + ((u >> 16) & 1u)) >> 16;
    return (unsigned short)r;
}

__device__ __forceinline__ float softplus_f(float v) {
    return v > 20.f ? v : log1pf(__expf(v));
}

__device__ __forceinline__ void gload_lds16(const void* g, void* l) {
    __builtin_amdgcn_global_load_lds(
        (const __attribute__((address_space(1))) unsigned int*)g,
        (__attribute__((address_space(3))) unsigned int*)l, 16, 0, 0);
}

// ---------------- f32 -> bf16 conversion ----------------
__global__ __launch_bounds__(256) void conv_bf16(const float4* __restrict__ src,
                                                 ushort4* __restrict__ dst, int n4) {
    int i = blockIdx.x * 256 + threadIdx.x;
    if (i >= n4) return;
    float4 v = src[i];
    ushort4 o;
    o.x = f2bf(v.x); o.y = f2bf(v.y); o.z = f2bf(v.z); o.w = f2bf(v.w);
    dst[i] = o;
}

// ---------------- delta GEMM: S = x @ W^T, softplus+sum over e -> atomicAdd ----------------
// 128x128 tile, BK=64, 4 waves (2x2 of 64x64), 16x16x32 bf16 MFMA.
// LDS layout: As[128 rows][64 cols bf16] with byte col swizzled by ((row&7)<<4); Bs at +16384.
// global_load_lds writes linearly (base + lane*16), so the SOURCE column is pre-swizzled.
__global__ __launch_bounds__(256) void gemm_delta(
    const unsigned short* __restrict__ xb, const unsigned short* __restrict__ wb,
    const float* __restrict__ b_delta, float* __restrict__ delta_raw)
{
    __shared__ char lds[32768];
    int bid = blockIdx.x;
    int swz = (bid & 7) * 128 + (bid >> 3);   // XCD-aware (1024 % 8 == 0, bijective)
    int rb = swz >> 3, eb = swz & 7;
    int row0 = rb * 128, e0 = eb * 128;
    int tid = threadIdx.x;
    int lane = tid & 63, w = tid >> 6;
    int wr = w >> 1, wc = w & 1;
    int lm = lane & 15, lk = lane >> 4;

    // pre-swizzled source column (elements): csrc_bytes = p ^ ((row&7)<<4), p=(lane&7)*16
    int colsw = ((lane & 7) * 8) ^ ((lane >> 3) << 3);
    int rsub = lane >> 3;     // row within 8-row region == row&7

    f32x4 acc[4][4];
    #pragma unroll
    for (int m = 0; m < 4; ++m)
        #pragma unroll
        for (int n = 0; n < 4; ++n)
            acc[m][n] = (f32x4){0.f, 0.f, 0.f, 0.f};

    for (int k0 = 0; k0 < DM; k0 += 64) {
        __syncthreads();   // prior compute done before overwrite
        #pragma unroll
        for (int j = 0; j < 4; ++j) {
            int region = w * 4 + j;           // 0..15, each = 8 rows x 128B
            int r0 = region * 8 + rsub;
            const unsigned short* gA = xb + (size_t)(row0 + r0) * DM + k0 + colsw;
            const unsigned short* gB = wb + (size_t)(e0  + r0) * DM + k0 + colsw;
            gload_lds16(gA, lds + region * 1024);
            gload_lds16(gB, lds + 16384 + region * 1024);
        }
        __syncthreads();   // drains vmcnt(0): LDS tiles ready
        #pragma unroll
        for (int kk = 0; kk < 2; ++kk) {
            bf16x8 a[4], b[4];
            #pragma unroll
            for (int m = 0; m < 4; ++m) {
                int r = wr * 64 + m * 16 + lm;
                int cb = (kk * 64 + lk * 16) ^ ((r & 7) << 4);
                a[m] = *(const bf16x8*)(lds + r * 128 + cb);
            }
            #pragma unroll
            for (int n = 0; n < 4; ++n) {
                int r = wc * 64 + n * 16 + lm;
                int cb = (kk * 64 + lk * 16) ^ ((r & 7) << 4);
                b[n] = *(const bf16x8*)(lds + 16384 + r * 128 + cb);
            }
            #pragma unroll
            for (int m = 0; m < 4; ++m)
                #pragma unroll
                for (int n = 0; n < 4; ++n)
                    acc[m][n] = __builtin_amdgcn_mfma_f32_16x16x32_bf16(a[m], b[n], acc[m][n], 0, 0, 0);
        }
    }

    // epilogue: softplus(S + b_delta), reduce over the 64 cols this wave owns, atomicAdd per row
    float bd[4];
    #pragma unroll
    for (int n = 0; n < 4; ++n) bd[n] = b_delta[e0 + wc * 64 + n * 16 + lm];
    #pragma unroll
    for (int m = 0; m < 4; ++m) {
        #pragma unroll
        for (int r = 0; r < 4; ++r) {
            float s = 0.f;
            #pragma unroll
            for (int n = 0; n < 4; ++n) s += softplus_f(acc[m][n][r] + bd[n]);
            s += __shfl_xor(s, 1, 16);
            s += __shfl_xor(s, 2, 16);
            s += __shfl_xor(s, 4, 16);
            s += __shfl_xor(s, 8, 16);
            if (lm == 0) {
                int row = row0 + wr * 64 + m * 16 + lk * 4 + r;  // C/D: row=(lane>>4)*4+reg
                atomicAdd(&delta_raw[row], s);
            }
        }
    }
}

// ---------------- Bx[i,n] = sum_d x[i,d]*B[n,d] ----------------
__global__ __launch_bounds__(256) void bx_kernel(
    const float* __restrict__ x, const float* __restrict__ B, float* __restrict__ Bx)
{
    int tid = threadIdx.x, lane = tid & 63, w = tid >> 6;
    int i = blockIdx.x * 4 + w;
    const float* xr = x + (size_t)i * DM;
    float acc[NS];
    #pragma unroll
    for (int n = 0; n < NS; ++n) acc[n] = 0.f;
    for (int d0 = 0; d0 < DM; d0 += 64) {
        float xv = xr[d0 + lane];
        #pragma unroll
        for (int n = 0; n < NS; ++n) acc[n] += xv * B[n * DM + d0 + lane];
    }
    #pragma unroll
    for (int n = 0; n < NS; ++n) {
        #pragma unroll
        for (int off = 32; off > 0; off >>= 1) acc[n] += __shfl_down(acc[n], off);
    }
    if (lane == 0) {
        #pragma unroll
        for (int n = 0; n < NS; ++n) Bx[(size_t)i * NS + n] = acc[n];
    }
}

// ---------------- scan pass 1: per-chunk (P = prod dA, h_local) ----------------
__global__ __launch_bounds__(64) void scan_pass1(
    const float* __restrict__ delta_raw, const float* __restrict__ Bx,
    const float* __restrict__ A_log, float* __restrict__ cP, float* __restrict__ cH)
{
    __shared__ float dl[LC];
    __shared__ float bxl[LC * NS];
    int bid = blockIdx.x;
    int b = bid >> 7, c = bid & 127;
    int l0 = c * LC;
    int t = threadIdx.x;
    size_t base = (size_t)b * LSEQ + l0;
    if (t < LC) dl[t] = delta_raw[base + t] * (1.f / 1024.f);
    const float4* src = (const float4*)(Bx + base * NS);   // LC*NS = 512 floats = 128 f4
    float4* dst = (float4*)bxl;
    dst[t] = src[t];
    dst[t + 64] = src[t + 64];
    __syncthreads();
    if (t < NS) {
        float a = -__expf(A_log[t]);
        float P = 1.f, h = 0.f;
        #pragma unroll
        for (int s = 0; s < LC; ++s) {
            float dlt = dl[s];
            float dA = __expf(dlt * a);
            h = dA * h + dlt * bxl[s * NS + t];
            P *= dA;
        }
        int idx = (b * NC + c) * NS + t;
        cP[idx] = P; cH[idx] = h;
    }
}

// ---------------- scan pass 2: serial combine of chunk carries ----------------
__global__ __launch_bounds__(64) void scan_pass2(
    const float* __restrict__ cP, const float* __restrict__ cH, float* __restrict__ h0)
{
    __shared__ float sp[NB * NC * NS];   // 8192 f = 32 KB
    __shared__ float sh[NB * NC * NS];
    int t = threadIdx.x;
    const float4* p4 = (const float4*)cP;
    const float4* h4 = (const float4*)cH;
    float4* sp4 = (float4*)sp;
    float4* sh4 = (float4*)sh;
    for (int i = t; i < (NB * NC * NS) / 4; i += 64) { sp4[i] = p4[i]; sh4[i] = h4[i]; }
    __syncthreads();
    int b = t >> 4, n = t & 15;
    float h = 0.f;
    for (int c = 0; c < NC; ++c) {
        int idx = (b * NC + c) * NS + n;
        h0[idx] = h;
        h = sp[idx] * h + sh[idx];
    }
}

// ---------------- pass 3: regenerate hs per chunk, fused y = hs@C^T + D*x ----------------
__global__ __launch_bounds__(256) void y_kernel(
    const float* __restrict__ x, const float* __restrict__ delta_raw,
    const float* __restrict__ Bx, const float* __restrict__ A_log,
    const float* __restrict__ h0, const float* __restrict__ C,
    const float* __restrict__ Dv, float* __restrict__ y)
{
    __shared__ float dl[LC];
    __shared__ float bxl[LC * NS];
    __shared__ float hsl[LC * NS];
    int bid = blockIdx.x;
    int b = bid >> 7, c = bid & 127;
    int l0 = c * LC;
    int t = threadIdx.x;
    size_t base = (size_t)b * LSEQ + l0;
    if (t < LC) dl[t] = delta_raw[base + t] * (1.f / 1024.f);
    if (t < 128) ((float4*)bxl)[t] = ((const float4*)(Bx + base * NS))[t];
    __syncthreads();
    if (t < NS) {
        float a = -__expf(A_log[t]);
        float h = h0[(b * NC + c) * NS + t];
        #pragma unroll
        for (int s = 0; s < LC; ++s) {
            float dlt = dl[s];
            float dA = __expf(dlt * a);
            h = dA * h + dlt * bxl[s * NS + t];
            hsl[s * NS + t] = h;
        }
    }
    __syncthreads();

    // thread owns 4 consecutive d columns; C rows held in registers
    int d0 = t * 4;
    float cr[4][NS];
    #pragma unroll
    for (int dd = 0; dd < 4; ++dd)
        #pragma unroll
        for (int nn = 0; nn < 4; ++nn) {
            float4 c4 = ((const float4*)C)[((d0 + dd) * NS + nn * 4) >> 2];
            cr[dd][nn * 4 + 0] = c4.x; cr[dd][nn * 4 + 1] = c4.y;
            cr[dd][nn * 4 + 2] = c4.z; cr[dd][nn * 4 + 3] = c4.w;
        }
    float4 dv = ((const float4*)Dv)[t];
    const float4* xr = (const float4*)(x + base * DM) + t;
    float4* yr = (float4*)(y + base * DM) + t;
    for (int s = 0; s < LC; ++s) {
        float hv[NS];
        #pragma unroll
        for (int n = 0; n < NS; ++n) hv[n] = hsl[s * NS + n];   // broadcast reads
        float4 xv = xr[s * 256];
        float4 o;
        o.x = dv.x * xv.x; o.y = dv.y * xv.y; o.z = dv.z * xv.z; o.w = dv.w * xv.w;
        #pragma unroll
        for (int n = 0; n < NS; ++n) {
            o.x += hv[n] * cr[0][n];
            o.y += hv[n] * cr[1][n];
            o.z += hv[n] * cr[2][n];
            o.w += hv[n] * cr[3][n];
        }
        yr[s * 256] = o;
    }
}

extern "C" void kernel_launch(void* const* d_in, const int* in_sizes, int n_in,
                              void* d_out, int out_size, void* d_ws, size_t ws_size,
                              hipStream_t stream)
{
    const float* x     = (const float*)d_in[0];
    const float* A_log = (const float*)d_in[1];
    const float* B     = (const float*)d_in[2];
    const float* C     = (const float*)d_in[3];
    const float* Dv    = (const float*)d_in[4];
    const float* Wd    = (const float*)d_in[5];
    const float* bd    = (const float*)d_in[6];
    float* y = (float*)d_out;

    char* ws = (char*)d_ws;
    unsigned short* xb = (unsigned short*)ws;                  // 33,554,432 B
    unsigned short* wb = (unsigned short*)(ws + 33554432);     //  2,097,152 B
    float* delta_raw   = (float*)(ws + 35651584);              //     65,536 B
    float* Bx          = (float*)(ws + 35717120);              //  1,048,576 B
    float* cP          = (float*)(ws + 36765696);              //     32,768 B
    float* cH          = (float*)(ws + 36798464);              //     32,768 B
    float* h0          = (float*)(ws + 36831232);              //     32,768 B

    conv_bf16<<<16384, 256, 0, stream>>>((const float4*)x,  (ushort4*)xb, 4194304);
    conv_bf16<<<1024,  256, 0, stream>>>((const float4*)Wd, (ushort4*)wb, 262144);
    hipMemsetAsync(delta_raw, 0, 65536, stream);
    gemm_delta<<<1024, 256, 0, stream>>>(xb, wb, bd, delta_raw);
    bx_kernel<<<MTOT / 4, 256, 0, stream>>>(x, B, Bx);
    scan_pass1<<<NB * NC, 64, 0, stream>>>(delta_raw, Bx, A_log, cP, cH);
    scan_pass2<<<1, 64, 0, stream>>>(cP, cH, h0);
    y_kernel<<<NB * NC, 256, 0, stream>>>(x, delta_raw, Bx, A_log, h0, C, Dv, y);
}

// Round 2
// 162.279 us; speedup vs baseline: 1.1998x; 1.1998x over previous
//
#include <hip/hip_runtime.h>
#include <hip/hip_bf16.h>
#include <stdint.h>

#define DM 1024
#define NS 16
#define LSEQ 4096
#define NB 4
#define MTOT (NB*LSEQ)   // 16384
#define NC 128           // scan chunks per sequence
#define LC 32            // LSEQ/NC

typedef __attribute__((ext_vector_type(8))) short bf16x8;
typedef __attribute__((ext_vector_type(4))) float f32x4;

__device__ __forceinline__ unsigned short f2bf(float f) {
    unsigned int u = __float_as_uint(f);
    unsigned int r = (u + 0x7FFFu + ((u >> 16) & 1u)) >> 16;
    return (unsigned short)r;
}

__device__ __forceinline__ float softplus_f(float v) {
    return v > 20.f ? v : log1pf(__expf(v));
}

__device__ __forceinline__ void gload_lds16(const void* g, void* l) {
    __builtin_amdgcn_global_load_lds(
        (const __attribute__((address_space(1))) unsigned int*)g,
        (__attribute__((address_space(3))) unsigned int*)l, 16, 0, 0);
}

// ---------------- f32 -> bf16 conversion ----------------
__global__ __launch_bounds__(256) void conv_bf16(const float4* __restrict__ src,
                                                 ushort4* __restrict__ dst, int n4) {
    int i = blockIdx.x * 256 + threadIdx.x;
    if (i >= n4) return;
    float4 v = src[i];
    ushort4 o;
    o.x = f2bf(v.x); o.y = f2bf(v.y); o.z = f2bf(v.z); o.w = f2bf(v.w);
    dst[i] = o;
}

// ---------------- delta GEMM: S = x @ W^T, softplus+sum over e -> atomicAdd ----------------
// 128x128 tile, BK=64, 4 waves (2x2 of 64x64), 16x16x32 bf16 MFMA.
// T3 2-phase: double-buffered LDS (2 x 32KB), prefetch next tile before compute,
// raw s_barrier + explicit vmcnt(0) AFTER compute (never __syncthreads' drain
// between issue and compute). LDS col bytes swizzled by ((row&7)<<4); since
// global_load_lds writes linearly, the SOURCE column is pre-swizzled instead.
__global__ __launch_bounds__(256) void gemm_delta(
    const unsigned short* __restrict__ xb, const unsigned short* __restrict__ wb,
    const float* __restrict__ b_delta, float* __restrict__ delta_raw)
{
    __shared__ char lds[65536];
    int bid = blockIdx.x;
    int swz = (bid & 7) * 128 + (bid >> 3);   // XCD-aware (1024 % 8 == 0, bijective)
    int rb = swz >> 3, eb = swz & 7;
    int row0 = rb * 128, e0 = eb * 128;
    int tid = threadIdx.x;
    int lane = tid & 63, w = tid >> 6;
    int wr = w >> 1, wc = w & 1;
    int lm = lane & 15, lk = lane >> 4;

    // pre-swizzled source column (elements): csrc_bytes = p ^ ((row&7)<<4), p=(lane&7)*16
    int colsw = ((lane & 7) * 8) ^ ((lane >> 3) << 3);
    int rsub = lane >> 3;     // row within 8-row region == row&7

    // per-thread global source pointers (k0 added per iteration)
    const unsigned short* pA[4];
    const unsigned short* pB[4];
    #pragma unroll
    for (int j = 0; j < 4; ++j) {
        int region = w * 4 + j;
        int r0 = region * 8 + rsub;
        pA[j] = xb + (size_t)(row0 + r0) * DM + colsw;
        pB[j] = wb + (size_t)(e0  + r0) * DM + colsw;
    }

    f32x4 acc[4][4];
    #pragma unroll
    for (int m = 0; m < 4; ++m)
        #pragma unroll
        for (int n = 0; n < 4; ++n)
            acc[m][n] = (f32x4){0.f, 0.f, 0.f, 0.f};

    auto stage = [&](int base, int k0) {
        #pragma unroll
        for (int j = 0; j < 4; ++j) {
            int region = w * 4 + j;
            gload_lds16(pA[j] + k0, lds + base + region * 1024);
            gload_lds16(pB[j] + k0, lds + base + 16384 + region * 1024);
        }
    };

    auto compute = [&](int base) {
        __builtin_amdgcn_s_setprio(1);
        #pragma unroll
        for (int kk = 0; kk < 2; ++kk) {
            bf16x8 a[4], b[4];
            #pragma unroll
            for (int m = 0; m < 4; ++m) {
                int r = wr * 64 + m * 16 + lm;
                int cb = (kk * 64 + lk * 16) ^ ((r & 7) << 4);
                a[m] = *(const bf16x8*)(lds + base + r * 128 + cb);
            }
            #pragma unroll
            for (int n = 0; n < 4; ++n) {
                int r = wc * 64 + n * 16 + lm;
                int cb = (kk * 64 + lk * 16) ^ ((r & 7) << 4);
                b[n] = *(const bf16x8*)(lds + base + 16384 + r * 128 + cb);
            }
            #pragma unroll
            for (int m = 0; m < 4; ++m)
                #pragma unroll
                for (int n = 0; n < 4; ++n)
                    acc[m][n] = __builtin_amdgcn_mfma_f32_16x16x32_bf16(a[m], b[n], acc[m][n], 0, 0, 0);
        }
        __builtin_amdgcn_s_setprio(0);
    };

    // prologue: stage tile 0, wait, barrier
    stage(0, 0);
    asm volatile("s_waitcnt vmcnt(0)" ::: "memory");
    __builtin_amdgcn_s_barrier();

    int cur = 0;
    for (int t = 0; t < 15; ++t) {
        stage(cur ^ 32768, (t + 1) << 6);   // prefetch next tile into other buffer
        compute(cur);                        // MFMA on current (hides load latency)
        asm volatile("s_waitcnt vmcnt(0)" ::: "memory");
        __builtin_amdgcn_s_barrier();
        cur ^= 32768;
    }
    compute(cur);                            // last tile, no prefetch

    // epilogue: softplus(S + b_delta), reduce over the 64 cols this wave owns, atomicAdd per row
    float bd[4];
    #pragma unroll
    for (int n = 0; n < 4; ++n) bd[n] = b_delta[e0 + wc * 64 + n * 16 + lm];
    #pragma unroll
    for (int m = 0; m < 4; ++m) {
        #pragma unroll
        for (int r = 0; r < 4; ++r) {
            float s = 0.f;
            #pragma unroll
            for (int n = 0; n < 4; ++n) s += softplus_f(acc[m][n][r] + bd[n]);
            s += __shfl_xor(s, 1, 16);
            s += __shfl_xor(s, 2, 16);
            s += __shfl_xor(s, 4, 16);
            s += __shfl_xor(s, 8, 16);
            if (lm == 0) {
                int row = row0 + wr * 64 + m * 16 + lk * 4 + r;  // C/D: row=(lane>>4)*4+reg
                atomicAdd(&delta_raw[row], s);
            }
        }
    }
}

// ---------------- Bx = x @ B^T via MFMA (M=16384, N=16, K=1024), reads bf16 xb ----------------
// wave handles 16 rows; a-frag = x rows, b-frag = B rows; D: col(lane&15)=n, row=(lane>>4)*4+r
__global__ __launch_bounds__(256) void bx_mfma(
    const unsigned short* __restrict__ xb, const unsigned short* __restrict__ bbf,
    float* __restrict__ Bx)
{
    int tid = threadIdx.x, lane = tid & 63, w = tid >> 6;
    int rb = blockIdx.x * 4 + w;          // 0..1023
    int r0 = rb * 16;
    int lm = lane & 15, lk = lane >> 4;
    const unsigned short* pa = xb + (size_t)(r0 + lm) * DM + lk * 8;
    const unsigned short* pb = bbf + (size_t)lm * DM + lk * 8;
    f32x4 acc = (f32x4){0.f, 0.f, 0.f, 0.f};
    #pragma unroll 4
    for (int k0 = 0; k0 < DM; k0 += 32) {
        bf16x8 a = *(const bf16x8*)(pa + k0);
        bf16x8 b = *(const bf16x8*)(pb + k0);
        acc = __builtin_amdgcn_mfma_f32_16x16x32_bf16(a, b, acc, 0, 0, 0);
    }
    #pragma unroll
    for (int r = 0; r < 4; ++r)
        Bx[(size_t)(r0 + lk * 4 + r) * NS + lm] = acc[r];
}

// ---------------- scan pass 1: per-chunk (P = prod dA, h_local) ----------------
__global__ __launch_bounds__(64) void scan_pass1(
    const float* __restrict__ delta_raw, const float* __restrict__ Bx,
    const float* __restrict__ A_log, float* __restrict__ cP, float* __restrict__ cH)
{
    __shared__ float dl[LC];
    __shared__ float bxl[LC * NS];
    int bid = blockIdx.x;
    int b = bid >> 7, c = bid & 127;
    int l0 = c * LC;
    int t = threadIdx.x;
    size_t base = (size_t)b * LSEQ + l0;
    if (t < LC) dl[t] = delta_raw[base + t] * (1.f / 1024.f);
    const float4* src = (const float4*)(Bx + base * NS);   // LC*NS = 512 floats = 128 f4
    float4* dst = (float4*)bxl;
    dst[t] = src[t];
    dst[t + 64] = src[t + 64];
    __syncthreads();
    if (t < NS) {
        float a = -__expf(A_log[t]);
        float P = 1.f, h = 0.f;
        #pragma unroll
        for (int s = 0; s < LC; ++s) {
            float dlt = dl[s];
            float dA = __expf(dlt * a);
            h = dA * h + dlt * bxl[s * NS + t];
            P *= dA;
        }
        int idx = (b * NC + c) * NS + t;
        cP[idx] = P; cH[idx] = h;
    }
}

// ---------------- scan pass 2: serial combine of chunk carries ----------------
__global__ __launch_bounds__(64) void scan_pass2(
    const float* __restrict__ cP, const float* __restrict__ cH, float* __restrict__ h0)
{
    __shared__ float sp[NB * NC * NS];   // 8192 f = 32 KB
    __shared__ float sh[NB * NC * NS];
    int t = threadIdx.x;
    const float4* p4 = (const float4*)cP;
    const float4* h4 = (const float4*)cH;
    float4* sp4 = (float4*)sp;
    float4* sh4 = (float4*)sh;
    for (int i = t; i < (NB * NC * NS) / 4; i += 64) { sp4[i] = p4[i]; sh4[i] = h4[i]; }
    __syncthreads();
    int b = t >> 4, n = t & 15;
    float h = 0.f;
    for (int c = 0; c < NC; ++c) {
        int idx = (b * NC + c) * NS + n;
        h0[idx] = h;
        h = sp[idx] * h + sh[idx];
    }
}

// ---------------- pass 3: regenerate hs per chunk, fused y = hs@C^T + D*x ----------------
__global__ __launch_bounds__(256) void y_kernel(
    const float* __restrict__ x, const float* __restrict__ delta_raw,
    const float* __restrict__ Bx, const float* __restrict__ A_log,
    const float* __restrict__ h0, const float* __restrict__ C,
    const float* __restrict__ Dv, float* __restrict__ y)
{
    __shared__ float dl[LC];
    __shared__ float bxl[LC * NS];
    __shared__ float hsl[LC * NS];
    int bid = blockIdx.x;
    int b = bid >> 7, c = bid & 127;
    int l0 = c * LC;
    int t = threadIdx.x;
    size_t base = (size_t)b * LSEQ + l0;
    if (t < LC) dl[t] = delta_raw[base + t] * (1.f / 1024.f);
    if (t < 128) ((float4*)bxl)[t] = ((const float4*)(Bx + base * NS))[t];
    __syncthreads();
    if (t < NS) {
        float a = -__expf(A_log[t]);
        float h = h0[(b * NC + c) * NS + t];
        #pragma unroll
        for (int s = 0; s < LC; ++s) {
            float dlt = dl[s];
            float dA = __expf(dlt * a);
            h = dA * h + dlt * bxl[s * NS + t];
            hsl[s * NS + t] = h;
        }
    }
    __syncthreads();

    // thread owns 4 consecutive d columns; C rows held in registers
    int d0 = t * 4;
    float cr[4][NS];
    #pragma unroll
    for (int dd = 0; dd < 4; ++dd)
        #pragma unroll
        for (int nn = 0; nn < 4; ++nn) {
            float4 c4 = ((const float4*)C)[((d0 + dd) * NS + nn * 4) >> 2];
            cr[dd][nn * 4 + 0] = c4.x; cr[dd][nn * 4 + 1] = c4.y;
            cr[dd][nn * 4 + 2] = c4.z; cr[dd][nn * 4 + 3] = c4.w;
        }
    float4 dv = ((const float4*)Dv)[t];
    const float4* xr = (const float4*)(x + base * DM) + t;
    float4* yr = (float4*)(y + base * DM) + t;
    for (int s = 0; s < LC; ++s) {
        float hv[NS];
        #pragma unroll
        for (int n = 0; n < NS; ++n) hv[n] = hsl[s * NS + n];   // broadcast reads
        float4 xv = xr[s * 256];
        float4 o;
        o.x = dv.x * xv.x; o.y = dv.y * xv.y; o.z = dv.z * xv.z; o.w = dv.w * xv.w;
        #pragma unroll
        for (int n = 0; n < NS; ++n) {
            o.x += hv[n] * cr[0][n];
            o.y += hv[n] * cr[1][n];
            o.z += hv[n] * cr[2][n];
            o.w += hv[n] * cr[3][n];
        }
        yr[s * 256] = o;
    }
}

extern "C" void kernel_launch(void* const* d_in, const int* in_sizes, int n_in,
                              void* d_out, int out_size, void* d_ws, size_t ws_size,
                              hipStream_t stream)
{
    const float* x     = (const float*)d_in[0];
    const float* A_log = (const float*)d_in[1];
    const float* B     = (const float*)d_in[2];
    const float* C     = (const float*)d_in[3];
    const float* Dv    = (const float*)d_in[4];
    const float* Wd    = (const float*)d_in[5];
    const float* bd    = (const float*)d_in[6];
    float* y = (float*)d_out;

    char* ws = (char*)d_ws;
    unsigned short* xb = (unsigned short*)ws;                  // 33,554,432 B
    unsigned short* wb = (unsigned short*)(ws + 33554432);     //  2,097,152 B
    float* delta_raw   = (float*)(ws + 35651584);              //     65,536 B
    float* Bx          = (float*)(ws + 35717120);              //  1,048,576 B
    float* cP          = (float*)(ws + 36765696);              //     32,768 B
    float* cH          = (float*)(ws + 36798464);              //     32,768 B
    float* h0          = (float*)(ws + 36831232);              //     32,768 B
    unsigned short* bbf= (unsigned short*)(ws + 36864000);     //     32,768 B

    conv_bf16<<<16384, 256, 0, stream>>>((const float4*)x,  (ushort4*)xb, 4194304);
    conv_bf16<<<1024,  256, 0, stream>>>((const float4*)Wd, (ushort4*)wb, 262144);
    conv_bf16<<<16,    256, 0, stream>>>((const float4*)B,  (ushort4*)bbf, 4096);
    hipMemsetAsync(delta_raw, 0, 65536, stream);
    gemm_delta<<<1024, 256, 0, stream>>>(xb, wb, bd, delta_raw);
    bx_mfma<<<256, 256, 0, stream>>>(xb, bbf, Bx);
    scan_pass1<<<NB * NC, 64, 0, stream>>>(delta_raw, Bx, A_log, cP, cH);
    scan_pass2<<<1, 64, 0, stream>>>(cP, cH, h0);
    y_kernel<<<NB * NC, 256, 0, stream>>>(x, delta_raw, Bx, A_log, h0, C, Dv, y);
}

// Round 4
// 116.358 us; speedup vs baseline: 1.6733x; 1.3946x over previous
//
#include <hip/hip_runtime.h>
#include <hip/hip_bf16.h>
#include <stdint.h>

#define DM 1024
#define NS 16
#define LSEQ 4096
#define NB 4
#define MTOT (NB*LSEQ)   // 16384
#define NC 128           // scan chunks per sequence
#define LC 32            // LSEQ/NC

typedef __attribute__((ext_vector_type(8))) short bf16x8;
typedef __attribute__((ext_vector_type(4))) float f32x4;

__device__ __forceinline__ unsigned short f2bf(float f) {
    unsigned int u = __float_as_uint(f);
    unsigned int r = (u + 0x7FFFu + ((u >> 16) & 1u)) >> 16;
    return (unsigned short)r;
}

__device__ __forceinline__ float bf2f(unsigned short u) {
    return __uint_as_float(((unsigned int)u) << 16);
}

// fast softplus: v_exp_f32 + v_log_f32, no log1pf libcall
__device__ __forceinline__ float softplus_f(float v) {
    return v > 15.f ? v : __logf(1.f + __expf(v));
}

__device__ __forceinline__ void gload_lds16(const void* g, void* l) {
    __builtin_amdgcn_global_load_lds(
        (const __attribute__((address_space(1))) unsigned int*)g,
        (__attribute__((address_space(3))) unsigned int*)l, 16, 0, 0);
}

// ---------------- f32 -> bf16 conversion ----------------
__global__ __launch_bounds__(256) void conv_bf16(const float4* __restrict__ src,
                                                 ushort4* __restrict__ dst, int n4) {
    int i = blockIdx.x * 256 + threadIdx.x;
    if (i >= n4) return;
    float4 v = src[i];
    ushort4 o;
    o.x = f2bf(v.x); o.y = f2bf(v.y); o.z = f2bf(v.z); o.w = f2bf(v.w);
    dst[i] = o;
}

// ---------------- delta GEMM: S = x @ W^T, softplus+sum over e -> atomicAdd ----------------
// 128x128 tile, BK=64, 4 waves (2x2 of 64x64), 16x16x32 bf16 MFMA.
// T4 counted vmcnt, hardened: (a) k folded into POINTERS (builtin offset always 0 —
// its gfx950 LDS-side semantics are ambiguous); (b) wait+barrier FUSED into a single
// asm volatile with memory clobber so nothing can be scheduled between them and no
// memory op can cross (rule #18 class of bugs).
__global__ __launch_bounds__(256) void gemm_delta(
    const unsigned short* __restrict__ xb, const unsigned short* __restrict__ wb,
    const float* __restrict__ b_delta, float* __restrict__ delta_raw)
{
    __shared__ char lds[65536];
    int bid = blockIdx.x;
    int swz = (bid & 7) * 128 + (bid >> 3);   // XCD-aware (1024 % 8 == 0, bijective)
    int rb = swz >> 3, eb = swz & 7;
    int row0 = rb * 128, e0 = eb * 128;
    int tid = threadIdx.x;
    int lane = tid & 63, w = tid >> 6;
    int wr = w >> 1, wc = w & 1;
    int lm = lane & 15, lk = lane >> 4;

    // pre-swizzled source column (elements): csrc_bytes = p ^ ((row&7)<<4), p=(lane&7)*16
    int colsw = ((lane & 7) * 8) ^ ((lane >> 3) << 3);
    int rsub = lane >> 3;     // row within 8-row region == row&7

    const unsigned short* pA[4];
    const unsigned short* pB[4];
    #pragma unroll
    for (int j = 0; j < 4; ++j) {
        int region = w * 4 + j;
        int r0 = region * 8 + rsub;
        pA[j] = xb + (size_t)(row0 + r0) * DM + colsw;
        pB[j] = wb + (size_t)(e0  + r0) * DM + colsw;
    }

    f32x4 acc[4][4];
    #pragma unroll
    for (int m = 0; m < 4; ++m)
        #pragma unroll
        for (int n = 0; n < 4; ++n)
            acc[m][n] = (f32x4){0.f, 0.f, 0.f, 0.f};

#define STAGE(BUF, KOFF) do { \
    _Pragma("unroll") \
    for (int j = 0; j < 4; ++j) { \
        int region = w * 4 + j; \
        gload_lds16(pA[j] + (KOFF), lds + (BUF) + region * 1024); \
        gload_lds16(pB[j] + (KOFF), lds + (BUF) + 16384 + region * 1024); \
    } } while (0)

#define COMPUTE(BUF) do { \
    __builtin_amdgcn_s_setprio(1); \
    _Pragma("unroll") \
    for (int kk = 0; kk < 2; ++kk) { \
        bf16x8 a[4], b[4]; \
        _Pragma("unroll") \
        for (int m = 0; m < 4; ++m) { \
            int r = wr * 64 + m * 16 + lm; \
            int cb = (kk * 64 + lk * 16) ^ ((r & 7) << 4); \
            a[m] = *(const bf16x8*)(lds + (BUF) + r * 128 + cb); \
        } \
        _Pragma("unroll") \
        for (int n = 0; n < 4; ++n) { \
            int r = wc * 64 + n * 16 + lm; \
            int cb = (kk * 64 + lk * 16) ^ ((r & 7) << 4); \
            b[n] = *(const bf16x8*)(lds + (BUF) + 16384 + r * 128 + cb); \
        } \
        _Pragma("unroll") \
        for (int m = 0; m < 4; ++m) \
            _Pragma("unroll") \
            for (int n = 0; n < 4; ++n) \
                acc[m][n] = __builtin_amdgcn_mfma_f32_16x16x32_bf16(a[m], b[n], acc[m][n], 0, 0, 0); \
    } \
    __builtin_amdgcn_s_setprio(0); \
} while (0)

// stage next tile, wait for CURRENT tile (8 newest stay in flight), join, compute, join
#define KSTEP(CUR, NXT, KOFF) do { \
    STAGE(NXT, KOFF); \
    asm volatile("s_waitcnt vmcnt(8)\n\ts_barrier" ::: "memory"); \
    COMPUTE(CUR); \
    asm volatile("s_barrier" ::: "memory"); \
} while (0)

    STAGE(0, 0);                       // tile 0 -> buf0, 8 outstanding
    int koff = 64;
    #pragma unroll 1
    for (int it = 0; it < 7; ++it) {
        KSTEP(0, 32768, koff);         // compute even tile, stage odd
        KSTEP(32768, 0, koff + 64);    // compute odd tile,  stage even
        koff += 128;
    }
    KSTEP(0, 32768, 960);              // compute tile 14, stage tile 15
    asm volatile("s_waitcnt vmcnt(0)\n\ts_barrier" ::: "memory");
    COMPUTE(32768);                    // tile 15

#undef KSTEP
#undef COMPUTE
#undef STAGE

    // epilogue: softplus(S + b_delta), reduce over the 64 cols this wave owns, atomicAdd per row
    float bd[4];
    #pragma unroll
    for (int n = 0; n < 4; ++n) bd[n] = b_delta[e0 + wc * 64 + n * 16 + lm];
    #pragma unroll
    for (int m = 0; m < 4; ++m) {
        #pragma unroll
        for (int r = 0; r < 4; ++r) {
            float s = 0.f;
            #pragma unroll
            for (int n = 0; n < 4; ++n) s += softplus_f(acc[m][n][r] + bd[n]);
            s += __shfl_xor(s, 1, 16);
            s += __shfl_xor(s, 2, 16);
            s += __shfl_xor(s, 4, 16);
            s += __shfl_xor(s, 8, 16);
            if (lm == 0) {
                int row = row0 + wr * 64 + m * 16 + lk * 4 + r;  // C/D: row=(lane>>4)*4+reg
                atomicAdd(&delta_raw[row], s);
            }
        }
    }
}

// ---------------- Bx = x @ B^T via MFMA (M=16384, N=16, K=1024), reads bf16 xb ----------------
__global__ __launch_bounds__(256) void bx_mfma(
    const unsigned short* __restrict__ xb, const unsigned short* __restrict__ bbf,
    float* __restrict__ Bx)
{
    int tid = threadIdx.x, lane = tid & 63, w = tid >> 6;
    int rb = blockIdx.x * 4 + w;          // 0..1023
    int r0 = rb * 16;
    int lm = lane & 15, lk = lane >> 4;
    const unsigned short* pa = xb + (size_t)(r0 + lm) * DM + lk * 8;
    const unsigned short* pb = bbf + (size_t)lm * DM + lk * 8;
    f32x4 acc = (f32x4){0.f, 0.f, 0.f, 0.f};
    #pragma unroll 4
    for (int k0 = 0; k0 < DM; k0 += 32) {
        bf16x8 a = *(const bf16x8*)(pa + k0);
        bf16x8 b = *(const bf16x8*)(pb + k0);
        acc = __builtin_amdgcn_mfma_f32_16x16x32_bf16(a, b, acc, 0, 0, 0);
    }
    #pragma unroll
    for (int r = 0; r < 4; ++r)
        Bx[(size_t)(r0 + lk * 4 + r) * NS + lm] = acc[r];
}

// ---------------- scan pass 1: per-chunk (P = prod dA, h_local) ----------------
__global__ __launch_bounds__(64) void scan_pass1(
    const float* __restrict__ delta_raw, const float* __restrict__ Bx,
    const float* __restrict__ A_log, float* __restrict__ cP, float* __restrict__ cH)
{
    __shared__ float dl[LC];
    __shared__ float bxl[LC * NS];
    int bid = blockIdx.x;
    int b = bid >> 7, c = bid & 127;
    int l0 = c * LC;
    int t = threadIdx.x;
    size_t base = (size_t)b * LSEQ + l0;
    if (t < LC) dl[t] = delta_raw[base + t] * (1.f / 1024.f);
    const float4* src = (const float4*)(Bx + base * NS);
    float4* dst = (float4*)bxl;
    dst[t] = src[t];
    dst[t + 64] = src[t + 64];
    __syncthreads();
    if (t < NS) {
        float a = -__expf(A_log[t]);
        float P = 1.f, h = 0.f;
        #pragma unroll
        for (int s = 0; s < LC; ++s) {
            float dlt = dl[s];
            float dA = __expf(dlt * a);
            h = dA * h + dlt * bxl[s * NS + t];
            P *= dA;
        }
        int idx = (b * NC + c) * NS + t;
        cP[idx] = P; cH[idx] = h;
    }
}

// ---------------- scan pass 2: serial combine of chunk carries ----------------
__global__ __launch_bounds__(64) void scan_pass2(
    const float* __restrict__ cP, const float* __restrict__ cH, float* __restrict__ h0)
{
    __shared__ float sp[NB * NC * NS];
    __shared__ float sh[NB * NC * NS];
    int t = threadIdx.x;
    const float4* p4 = (const float4*)cP;
    const float4* h4 = (const float4*)cH;
    float4* sp4 = (float4*)sp;
    float4* sh4 = (float4*)sh;
    for (int i = t; i < (NB * NC * NS) / 4; i += 64) { sp4[i] = p4[i]; sh4[i] = h4[i]; }
    __syncthreads();
    int b = t >> 4, n = t & 15;
    float h = 0.f;
    for (int c = 0; c < NC; ++c) {
        int idx = (b * NC + c) * NS + n;
        h0[idx] = h;
        h = sp[idx] * h + sh[idx];
    }
}

// ---------------- pass 3: regenerate hs per chunk, fused y = hs@C^T + D*x ----------------
// reads bf16 xb (L3-hot, half the bytes of f32 x)
__global__ __launch_bounds__(256) void y_kernel(
    const unsigned short* __restrict__ xb, const float* __restrict__ delta_raw,
    const float* __restrict__ Bx, const float* __restrict__ A_log,
    const float* __restrict__ h0, const float* __restrict__ C,
    const float* __restrict__ Dv, float* __restrict__ y)
{
    __shared__ float dl[LC];
    __shared__ float bxl[LC * NS];
    __shared__ float hsl[LC * NS];
    int bid = blockIdx.x;
    int b = bid >> 7, c = bid & 127;
    int l0 = c * LC;
    int t = threadIdx.x;
    size_t base = (size_t)b * LSEQ + l0;
    if (t < LC) dl[t] = delta_raw[base + t] * (1.f / 1024.f);
    if (t < 128) ((float4*)bxl)[t] = ((const float4*)(Bx + base * NS))[t];
    __syncthreads();
    if (t < NS) {
        float a = -__expf(A_log[t]);
        float h = h0[(b * NC + c) * NS + t];
        #pragma unroll
        for (int s = 0; s < LC; ++s) {
            float dlt = dl[s];
            float dA = __expf(dlt * a);
            h = dA * h + dlt * bxl[s * NS + t];
            hsl[s * NS + t] = h;
        }
    }
    __syncthreads();

    int d0 = t * 4;
    float cr[4][NS];
    #pragma unroll
    for (int dd = 0; dd < 4; ++dd)
        #pragma unroll
        for (int nn = 0; nn < 4; ++nn) {
            float4 c4 = ((const float4*)C)[((d0 + dd) * NS + nn * 4) >> 2];
            cr[dd][nn * 4 + 0] = c4.x; cr[dd][nn * 4 + 1] = c4.y;
            cr[dd][nn * 4 + 2] = c4.z; cr[dd][nn * 4 + 3] = c4.w;
        }
    float4 dv = ((const float4*)Dv)[t];
    const ushort4* xr = (const ushort4*)(xb + base * DM) + t;
    float4* yr = (float4*)(y + base * DM) + t;
    for (int s = 0; s < LC; ++s) {
        float hv[NS];
        #pragma unroll
        for (int n = 0; n < NS; ++n) hv[n] = hsl[s * NS + n];
        ushort4 xv4 = xr[s * 256];
        float4 o;
        o.x = dv.x * bf2f(xv4.x); o.y = dv.y * bf2f(xv4.y);
        o.z = dv.z * bf2f(xv4.z); o.w = dv.w * bf2f(xv4.w);
        #pragma unroll
        for (int n = 0; n < NS; ++n) {
            o.x += hv[n] * cr[0][n];
            o.y += hv[n] * cr[1][n];
            o.z += hv[n] * cr[2][n];
            o.w += hv[n] * cr[3][n];
        }
        yr[s * 256] = o;
    }
}

extern "C" void kernel_launch(void* const* d_in, const int* in_sizes, int n_in,
                              void* d_out, int out_size, void* d_ws, size_t ws_size,
                              hipStream_t stream)
{
    const float* x     = (const float*)d_in[0];
    const float* A_log = (const float*)d_in[1];
    const float* B     = (const float*)d_in[2];
    const float* C     = (const float*)d_in[3];
    const float* Dv    = (const float*)d_in[4];
    const float* Wd    = (const float*)d_in[5];
    const float* bd    = (const float*)d_in[6];
    float* y = (float*)d_out;

    char* ws = (char*)d_ws;
    unsigned short* xb = (unsigned short*)ws;                  // 33,554,432 B
    unsigned short* wb = (unsigned short*)(ws + 33554432);     //  2,097,152 B
    float* delta_raw   = (float*)(ws + 35651584);              //     65,536 B
    float* Bx          = (float*)(ws + 35717120);              //  1,048,576 B
    float* cP          = (float*)(ws + 36765696);              //     32,768 B
    float* cH          = (float*)(ws + 36798464);              //     32,768 B
    float* h0          = (float*)(ws + 36831232);              //     32,768 B
    unsigned short* bbf= (unsigned short*)(ws + 36864000);     //     32,768 B

    conv_bf16<<<16384, 256, 0, stream>>>((const float4*)x,  (ushort4*)xb, 4194304);
    conv_bf16<<<1024,  256, 0, stream>>>((const float4*)Wd, (ushort4*)wb, 262144);
    conv_bf16<<<16,    256, 0, stream>>>((const float4*)B,  (ushort4*)bbf, 4096);
    hipMemsetAsync(delta_raw, 0, 65536, stream);
    gemm_delta<<<1024, 256, 0, stream>>>(xb, wb, bd, delta_raw);
    bx_mfma<<<256, 256, 0, stream>>>(xb, bbf, Bx);
    scan_pass1<<<NB * NC, 64, 0, stream>>>(delta_raw, Bx, A_log, cP, cH);
    scan_pass2<<<1, 64, 0, stream>>>(cP, cH, h0);
    y_kernel<<<NB * NC, 256, 0, stream>>>(xb, delta_raw, Bx, A_log, h0, C, Dv, y);
}